// Round 8
// baseline (290.883 us; speedup 1.0000x reference)
//
#include <hip/hip_runtime.h>
#include <hip/hip_bf16.h>

#define NN 50000
#define NE 600000
#define MM1_BLOCKS 782

typedef __attribute__((ext_vector_type(4))) float f32x4;
typedef __attribute__((ext_vector_type(8))) __bf16 bf16x8;

__device__ __forceinline__ unsigned pack2bf16(float x, float y) {
  __bf16 lo = (__bf16)x, hi = (__bf16)y;
  unsigned short ul = __builtin_bit_cast(unsigned short, lo);
  unsigned short uh = __builtin_bit_cast(unsigned short, hi);
  return (unsigned)ul | ((unsigned)uh << 16);
}

// ---------- CSR build ----------
__global__ void k_zero(int* __restrict__ degi) {
  int i = blockIdx.x * 256 + threadIdx.x;
  if (i < NN) degi[i] = 0;
}

// block-inclusive scan of PADDED degrees (rows padded to multiple of 4)
__global__ __launch_bounds__(256) void k_scan1(const int* __restrict__ degi, int* __restrict__ rp,
                                               int* __restrict__ bsum) {
  __shared__ int s[256];
  int gid = blockIdx.x * 256 + threadIdx.x;
  int d = (gid < NN) ? degi[gid] : 0;
  int pd = (d + 3) & ~3;
  s[threadIdx.x] = pd;
  __syncthreads();
  int acc = pd;
  for (int off = 1; off < 256; off <<= 1) {
    int add = (threadIdx.x >= off) ? s[threadIdx.x - off] : 0;
    __syncthreads();
    acc += add;
    s[threadIdx.x] = acc;
    __syncthreads();
  }
  if (gid < NN) rp[gid + 1] = acc;
  if (threadIdx.x == 255) bsum[blockIdx.x] = acc;
}

// finalize rp/cur/dinv + pre-zero pad slots; each block re-scans bsum locally (196 entries)
__global__ __launch_bounds__(256) void k_scan3z(int* __restrict__ rp, const int* __restrict__ bsum,
                                                const int* __restrict__ degi, int* __restrict__ cur,
                                                float* __restrict__ dinv, int2* __restrict__ edg,
                                                int nb) {
  __shared__ int s[256];
  int tid = threadIdx.x, bid = blockIdx.x;
  int v = (tid < nb) ? bsum[tid] : 0;
  s[tid] = v;
  __syncthreads();
  int acc = v;
  for (int off = 1; off < 256; off <<= 1) {
    int add = (tid >= off) ? s[tid - off] : 0;
    __syncthreads();
    acc += add;
    s[tid] = acc;
    __syncthreads();
  }
  int blkoff = (bid > 0) ? s[bid - 1] : 0;
  int gid = bid * 256 + tid;
  if (gid < NN) {
    int d = degi[gid];
    int pd = (d + 3) & ~3;
    int incl = rp[gid + 1] + blkoff;  // inclusive padded prefix through gid
    rp[gid + 1] = incl;
    int start = incl - pd;
    cur[gid] = start;
    dinv[gid] = rsqrtf((float)(d + 1));  // +1 self-loop; always > 0
    for (int j = start + d; j < incl; j++) edg[j] = make_int2(0, 0);  // pad slots, disjoint from fill
  }
  if (gid == 0) rp[0] = 0;
}

__global__ void k_fill(const int* __restrict__ srcv, const int* __restrict__ dstv,
                       int* __restrict__ cur, int2* __restrict__ edg, const float* __restrict__ dinv) {
  int e = blockIdx.x * 256 + threadIdx.x;
  if (e < NE) {
    int s = srcv[e], d = dstv[e];
    int p = atomicAdd(&cur[d], 1);
    edg[p] = make_int2(s, __float_as_int(dinv[s] * dinv[d]));
  }
}

// ---------- conflict-free W^T staging: wt[j][k] = W[k][j] ----------
__device__ __forceinline__ void stage_wt(const float* __restrict__ W, __bf16 (*wt)[136], int tid) {
  int j = tid & 127;
  int hi = tid >> 7;  // 0 or 1
#pragma unroll 4
  for (int it = 0; it < 32; ++it) {
    int kp = ((it << 1) + hi + (j >> 3)) & 63;
    float w0 = W[(kp * 2) * 128 + j];
    float w1 = W[(kp * 2 + 1) * 128 + j];
    *(unsigned*)(&wt[j][kp * 2]) = pack2bf16(w0, w1);
  }
}

// ---------- mm body: [16-row strip] @ [128,128] via MFMA ----------
template<int BR, bool IN_BF16, bool DUAL>
__device__ __forceinline__ void mm_body(const void* __restrict__ Xv, const __bf16 (*wt)[136],
                                        const float* __restrict__ bias, __bf16* __restrict__ Y,
                                        float* __restrict__ Yf, int strip, int lane) {
  int r16 = lane & 15, g = lane >> 4;
  bf16x8 a[4];
  if constexpr (IN_BF16) {
    const __bf16* xb = (const __bf16*)Xv + (size_t)(strip * 16 + r16) * 128 + g * 8;
#pragma unroll
    for (int ks = 0; ks < 4; ks++) a[ks] = *(const bf16x8*)(xb + ks * 32);
  } else {
    const float* xb = (const float*)Xv + (size_t)(strip * 16 + r16) * 128 + g * 8;
#pragma unroll
    for (int ks = 0; ks < 4; ks++) {
      f32x4 x0 = *(const f32x4*)(xb + ks * 32);
      f32x4 x1 = *(const f32x4*)(xb + ks * 32 + 4);
      bf16x8 v;
      v[0] = (__bf16)x0.x; v[1] = (__bf16)x0.y; v[2] = (__bf16)x0.z; v[3] = (__bf16)x0.w;
      v[4] = (__bf16)x1.x; v[5] = (__bf16)x1.y; v[6] = (__bf16)x1.z; v[7] = (__bf16)x1.w;
      a[ks] = v;
    }
  }
  f32x4 acc[8];
#pragma unroll
  for (int ct = 0; ct < 8; ct++) acc[ct] = (f32x4){0.f, 0.f, 0.f, 0.f};
#pragma unroll
  for (int ct = 0; ct < 8; ct++) {
    const __bf16* wrow = &wt[ct * 16 + r16][g * 8];
#pragma unroll
    for (int ks = 0; ks < 4; ks++) {
      bf16x8 b = *(const bf16x8*)(wrow + ks * 32);
      acc[ct] = __builtin_amdgcn_mfma_f32_16x16x32_bf16(a[ks], b, acc[ct], 0, 0, 0);
    }
  }
  int rbase = strip * 16 + g * 4;
#pragma unroll
  for (int ct = 0; ct < 8; ct++) {
    int col = ct * 16 + r16;
    float bv = (BR & 1) ? bias[col] : 0.f;
#pragma unroll
    for (int i = 0; i < 4; i++) {
      float v = acc[ct][i] + bv;
      if (BR & 2) v = fmaxf(v, 0.f);
      size_t idx = (size_t)(rbase + i) * 128 + col;
      Y[idx] = (__bf16)v;
      if constexpr (DUAL) Yf[idx] = v;
    }
  }
}

template<int BR, bool IN_BF16, bool DUAL>
__global__ __launch_bounds__(256) void k_mm128(const void* __restrict__ Xv, const float* __restrict__ W,
                                               const float* __restrict__ bias, __bf16* __restrict__ Y,
                                               float* __restrict__ Yf, int nrows) {
  __shared__ __bf16 wt[128][136];
  int tid = threadIdx.x;
  stage_wt(W, wt, tid);
  __syncthreads();
  int strip = blockIdx.x * 4 + (tid >> 6);
  if (strip * 16 >= nrows) return;
  mm_body<BR, IN_BF16, DUAL>(Xv, wt, bias, Y, Yf, strip, tid & 63);
}

// ---------- fused: blocks [0,MM1_BLOCKS) do mm1 (x@w1); rest do degree count ----------
__global__ __launch_bounds__(256) void k_mm1_count(const float* __restrict__ X, const float* __restrict__ W,
                                                   __bf16* __restrict__ Y,
                                                   const int* __restrict__ dstv, int* __restrict__ degi) {
  __shared__ __bf16 wt[128][136];
  int tid = threadIdx.x;
  if (blockIdx.x >= MM1_BLOCKS) {
    int e = (blockIdx.x - MM1_BLOCKS) * 256 + tid;
    if (e < NE) atomicAdd(&degi[dstv[e]], 1);
    return;
  }
  stage_wt(W, wt, tid);
  __syncthreads();
  int strip = blockIdx.x * 4 + (tid >> 6);
  if (strip * 16 >= NN) return;
  mm_body<0, false, false>(X, wt, nullptr, Y, nullptr, strip, tid & 63);
}

// ---------- task heads: bf16 [N,128] @ [128,50] -> y[t][n][c] fp32 ----------
__global__ __launch_bounds__(256) void k_head(const __bf16* __restrict__ H, const float* __restrict__ TW,
                                              const float* __restrict__ TB, float* __restrict__ Y) {
  __shared__ __bf16 wt[64][136];  // wt[o][k] = task_w[o/10][k][o%10], o<50; else 0
  int tid = threadIdx.x;
  for (int i = tid; i < 8192; i += 256) {
    int o = i >> 7, k = i & 127;
    float v = 0.f;
    if (o < 50) v = TW[(o / 10) * 1280 + k * 10 + (o % 10)];
    wt[o][k] = (__bf16)v;
  }
  __syncthreads();
  int lane = tid & 63;
  int strip = blockIdx.x * 4 + (tid >> 6);
  if (strip * 16 >= NN) return;
  int r16 = lane & 15, g = lane >> 4;
  const __bf16* xb = H + (size_t)(strip * 16 + r16) * 128 + g * 8;
  bf16x8 a[4];
#pragma unroll
  for (int ks = 0; ks < 4; ks++) a[ks] = *(const bf16x8*)(xb + ks * 32);
  f32x4 acc[4];
#pragma unroll
  for (int ct = 0; ct < 4; ct++) acc[ct] = (f32x4){0.f, 0.f, 0.f, 0.f};
#pragma unroll
  for (int ct = 0; ct < 4; ct++) {
    const __bf16* wrow = &wt[ct * 16 + r16][g * 8];
#pragma unroll
    for (int ks = 0; ks < 4; ks++) {
      bf16x8 b = *(const bf16x8*)(wrow + ks * 32);
      acc[ct] = __builtin_amdgcn_mfma_f32_16x16x32_bf16(a[ks], b, acc[ct], 0, 0, 0);
    }
  }
  int rbase = strip * 16 + g * 4;
#pragma unroll
  for (int ct = 0; ct < 4; ct++) {
    int o = ct * 16 + r16;
    if (o < 50) {
      int t = o / 10, c = o % 10;
      float tb = TB[o];
#pragma unroll
      for (int i = 0; i < 4; i++) {
        Y[(size_t)t * (NN * 10) + (size_t)(rbase + i) * 10 + c] = acc[ct][i] + tb;
      }
    }
  }
}

// ---------- XCD-quarter-split CSR pull aggregation ----------
// Table slice per quarter = 50000*32 cols*2B = 3.2 MB < 4 MB per-XCD L2.
// quarter = (blockIdx%8)>>1  ->  XCD pair {2q,2q+1} reads ONLY quarter q (heuristic %8 mapping;
// correctness independent of mapping). Edge metadata loaded non-temporally to protect L2.
// Wave: 4 edge-slots x 16 lanes; lane loads 1 uint (2 bf16 cols); shfl-reduce across slots.
__global__ __launch_bounds__(256) void k_agg(const unsigned* __restrict__ T, const int* __restrict__ rp,
                                             const int2* __restrict__ edg, const float* __restrict__ dinv,
                                             const float* __restrict__ bias, unsigned* __restrict__ H) {
  int bid = blockIdx.x;                 // 25000 blocks = 3125*8
  int wv = threadIdx.x >> 6;
  int lane = threadIdx.x & 63;
  int q = (bid >> 1) & 3;               // col quarter (== (bid%8)>>1)
  int pairIdx = ((((bid >> 3) << 1) | (bid & 1)) << 2) + wv;  // 0..24999 within quarter
  int nA = pairIdx * 2, nB = nA + 1;
  int e = lane >> 4;                    // edge slot 0..3
  int colOff = (q << 4) + (lane & 15);  // uint index within 64-uint row
  float axA = 0.f, ayA = 0.f, axB = 0.f, ayB = 0.f;
  int iA = rp[nA], eA = rp[nA + 1];
  int iB = rp[nB], eB = rp[nB + 1];
  const long long* edq = (const long long*)edg;
  while (iA < eA && iB < eB) {
    long long evA = __builtin_nontemporal_load(&edq[iA + e]);
    long long evB = __builtin_nontemporal_load(&edq[iB + e]);
    int sA = (int)(unsigned)evA, sB = (int)(unsigned)evB;
    float wA = __int_as_float((int)(evA >> 32));
    float wB = __int_as_float((int)(evB >> 32));
    unsigned rA = T[(size_t)sA * 64 + colOff];
    unsigned rB = T[(size_t)sB * 64 + colOff];
    axA = fmaf(__uint_as_float(rA << 16), wA, axA);
    ayA = fmaf(__uint_as_float(rA & 0xffff0000u), wA, ayA);
    axB = fmaf(__uint_as_float(rB << 16), wB, axB);
    ayB = fmaf(__uint_as_float(rB & 0xffff0000u), wB, ayB);
    iA += 4; iB += 4;
  }
  for (; iA < eA; iA += 4) {
    long long ev = __builtin_nontemporal_load(&edq[iA + e]);
    int s = (int)(unsigned)ev;
    float w = __int_as_float((int)(ev >> 32));
    unsigned r = T[(size_t)s * 64 + colOff];
    axA = fmaf(__uint_as_float(r << 16), w, axA);
    ayA = fmaf(__uint_as_float(r & 0xffff0000u), w, ayA);
  }
  for (; iB < eB; iB += 4) {
    long long ev = __builtin_nontemporal_load(&edq[iB + e]);
    int s = (int)(unsigned)ev;
    float w = __int_as_float((int)(ev >> 32));
    unsigned r = T[(size_t)s * 64 + colOff];
    axB = fmaf(__uint_as_float(r << 16), w, axB);
    ayB = fmaf(__uint_as_float(r & 0xffff0000u), w, ayB);
  }
  // reduce across the 4 edge slots (lanes c, c+16, c+32, c+48 hold same cols)
  axA += __shfl_xor(axA, 16); axA += __shfl_xor(axA, 32);
  ayA += __shfl_xor(ayA, 16); ayA += __shfl_xor(ayA, 32);
  axB += __shfl_xor(axB, 16); axB += __shfl_xor(axB, 32);
  ayB += __shfl_xor(ayB, 16); ayB += __shfl_xor(ayB, 32);
  // self-loop + bias + relu
  float diA = dinv[nA], diB = dinv[nB];
  unsigned sA = T[(size_t)nA * 64 + colOff];
  unsigned sB = T[(size_t)nB * 64 + colOff];
  axA = fmaf(__uint_as_float(sA << 16), diA * diA, axA);
  ayA = fmaf(__uint_as_float(sA & 0xffff0000u), diA * diA, ayA);
  axB = fmaf(__uint_as_float(sB << 16), diB * diB, axB);
  ayB = fmaf(__uint_as_float(sB & 0xffff0000u), diB * diB, ayB);
  float2 bv = ((const float2*)bias)[colOff];
  axA = fmaxf(axA + bv.x, 0.f); ayA = fmaxf(ayA + bv.y, 0.f);
  axB = fmaxf(axB + bv.x, 0.f); ayB = fmaxf(ayB + bv.y, 0.f);
  if (e == 0) {
    __builtin_nontemporal_store(pack2bf16(axA, ayA), &H[(size_t)nA * 64 + colOff]);
    __builtin_nontemporal_store(pack2bf16(axB, ayB), &H[(size_t)nB * 64 + colOff]);
  }
}

extern "C" void kernel_launch(void* const* d_in, const int* in_sizes, int n_in,
                              void* d_out, int out_size, void* d_ws, size_t ws_size,
                              hipStream_t stream) {
  (void)in_sizes; (void)n_in; (void)out_size; (void)ws_size;
  const float* x   = (const float*)d_in[0];
  const int*   ei  = (const int*)d_in[1];
  const float* w1  = (const float*)d_in[2];
  const float* b1  = (const float*)d_in[3];
  const float* w2  = (const float*)d_in[4];
  const float* b2  = (const float*)d_in[5];
  const float* fw1 = (const float*)d_in[6];
  const float* fb1 = (const float*)d_in[7];
  const float* fw2 = (const float*)d_in[8];
  const float* fb2 = (const float*)d_in[9];
  const float* tw  = (const float*)d_in[10];
  const float* tb  = (const float*)d_in[11];
  const int* srcv = ei;
  const int* dstv = ei + NE;

  char* wsb = (char*)d_ws;
  __bf16* bufT = (__bf16*)(wsb + 0);         // 12,800,000 B  [N,128] bf16
  __bf16* hbf  = (__bf16*)(wsb + 12800000);  // 12,800,000 B  [N,128] bf16
  int*    degi = (int*)(wsb + 25600000);     //    200,000 B
  int*    rp   = (int*)(wsb + 25800192);     //    200,004 B
  int*    cur  = (int*)(wsb + 26000640);     //    200,000 B
  int*    bsum = (int*)(wsb + 26200832);     //        784 B
  float*  dinv = (float*)(wsb + 26201856);   //    200,000 B
  int2*   edg  = (int2*)(wsb + 26402048);    //  7,600,000 B (pad-4 rows, <=800k slots)
  // total ~34 MB of 256 MB ws

  float* y_out = (float*)d_out;              // [5,50000,10]
  float* feat  = (float*)d_out + 2500000;    // [50000,128] feature_x fp32

  // --- CSR build (mm1 fused with count; independent work overlaps) ---
  k_zero<<<196, 256, 0, stream>>>(degi);
  k_mm1_count<<<MM1_BLOCKS + (NE + 255) / 256, 256, 0, stream>>>(x, w1, bufT, dstv, degi);
  k_scan1<<<196, 256, 0, stream>>>(degi, rp, bsum);
  k_scan3z<<<196, 256, 0, stream>>>(rp, bsum, degi, cur, dinv, edg, 196);
  k_fill<<<(NE + 255) / 256, 256, 0, stream>>>(srcv, dstv, cur, edg, dinv);

  // --- GCN layer 1 aggregation ---
  k_agg<<<25000, 256, 0, stream>>>((const unsigned*)bufT, rp, edg, dinv, b1, (unsigned*)hbf);
  // --- GCN layer 2 ---
  k_mm128<0, true, false><<<782, 256, 0, stream>>>(hbf, w2, nullptr, bufT, nullptr, NN);
  k_agg<<<25000, 256, 0, stream>>>((const unsigned*)bufT, rp, edg, dinv, b2, (unsigned*)hbf);
  // --- fc1: feature_x (fp32 to d_out, bf16 in-place for fc2) ---
  k_mm128<3, true, true><<<782, 256, 0, stream>>>(hbf, fw1, fb1, hbf, feat, NN);
  // --- fc2 ---
  k_mm128<3, true, false><<<782, 256, 0, stream>>>(hbf, fw2, fb2, bufT, nullptr, NN);
  // --- heads ---
  k_head<<<782, 256, 0, stream>>>(bufT, tw, tb, y_out);
}

// Round 9
// 182.605 us; speedup vs baseline: 1.5930x; 1.5930x over previous
//
#include <hip/hip_runtime.h>
#include <hip/hip_bf16.h>

#define NN 50000
#define NE 600000
#define MM1_BLOCKS 782
#define STRIDE 64  // fixed edge slots per node; P(deg>=64) ~ 1e-30 for Poisson(12)

typedef __attribute__((ext_vector_type(4))) float f32x4;
typedef __attribute__((ext_vector_type(8))) __bf16 bf16x8;

__device__ __forceinline__ unsigned pack2bf16(float x, float y) {
  __bf16 lo = (__bf16)x, hi = (__bf16)y;
  unsigned short ul = __builtin_bit_cast(unsigned short, lo);
  unsigned short uh = __builtin_bit_cast(unsigned short, hi);
  return (unsigned)ul | ((unsigned)uh << 16);
}

// ---------- CSR build (fixed stride, no scans) ----------
__global__ void k_zero(int* __restrict__ degi) {
  int i = blockIdx.x * 256 + threadIdx.x;
  if (i < NN) degi[i] = 0;
}

// per-node: cursor, dinv, zero pad slots [deg, pad8(deg))
__global__ void k_prep(const int* __restrict__ degi, int* __restrict__ cur,
                       float* __restrict__ dinv, int2* __restrict__ edg) {
  int n = blockIdx.x * 256 + threadIdx.x;
  if (n < NN) {
    int d = degi[n];
    int base = n * STRIDE;
    cur[n] = base;
    dinv[n] = rsqrtf((float)(d + 1));  // +1 self-loop; always > 0
    int pe = base + ((d + 7) & ~7);
    for (int j = base + d; j < pe; j++) edg[j] = make_int2(0, 0);  // weight-0: inert
  }
}

__global__ void k_fill(const int* __restrict__ srcv, const int* __restrict__ dstv,
                       int* __restrict__ cur, int2* __restrict__ edg, const float* __restrict__ dinv) {
  int e = blockIdx.x * 256 + threadIdx.x;
  if (e < NE) {
    int s = srcv[e], d = dstv[e];
    int p = atomicAdd(&cur[d], 1);
    edg[p] = make_int2(s, __float_as_int(dinv[s] * dinv[d]));
  }
}

// ---------- conflict-free W^T staging: wt[j][k] = W[k][j] ----------
__device__ __forceinline__ void stage_wt(const float* __restrict__ W, __bf16 (*wt)[136], int tid) {
  int j = tid & 127;
  int hi = tid >> 7;  // 0 or 1
#pragma unroll 4
  for (int it = 0; it < 32; ++it) {
    int kp = ((it << 1) + hi + (j >> 3)) & 63;
    float w0 = W[(kp * 2) * 128 + j];
    float w1 = W[(kp * 2 + 1) * 128 + j];
    *(unsigned*)(&wt[j][kp * 2]) = pack2bf16(w0, w1);
  }
}

// ---------- mm body: [16-row strip] @ [128,128] via MFMA ----------
template<int BR, bool IN_BF16, bool DUAL>
__device__ __forceinline__ void mm_body(const void* __restrict__ Xv, const __bf16 (*wt)[136],
                                        const float* __restrict__ bias, __bf16* __restrict__ Y,
                                        float* __restrict__ Yf, int strip, int lane) {
  int r16 = lane & 15, g = lane >> 4;
  bf16x8 a[4];
  if constexpr (IN_BF16) {
    const __bf16* xb = (const __bf16*)Xv + (size_t)(strip * 16 + r16) * 128 + g * 8;
#pragma unroll
    for (int ks = 0; ks < 4; ks++) a[ks] = *(const bf16x8*)(xb + ks * 32);
  } else {
    const float* xb = (const float*)Xv + (size_t)(strip * 16 + r16) * 128 + g * 8;
#pragma unroll
    for (int ks = 0; ks < 4; ks++) {
      f32x4 x0 = *(const f32x4*)(xb + ks * 32);
      f32x4 x1 = *(const f32x4*)(xb + ks * 32 + 4);
      bf16x8 v;
      v[0] = (__bf16)x0.x; v[1] = (__bf16)x0.y; v[2] = (__bf16)x0.z; v[3] = (__bf16)x0.w;
      v[4] = (__bf16)x1.x; v[5] = (__bf16)x1.y; v[6] = (__bf16)x1.z; v[7] = (__bf16)x1.w;
      a[ks] = v;
    }
  }
  f32x4 acc[8];
#pragma unroll
  for (int ct = 0; ct < 8; ct++) acc[ct] = (f32x4){0.f, 0.f, 0.f, 0.f};
#pragma unroll
  for (int ct = 0; ct < 8; ct++) {
    const __bf16* wrow = &wt[ct * 16 + r16][g * 8];
#pragma unroll
    for (int ks = 0; ks < 4; ks++) {
      bf16x8 b = *(const bf16x8*)(wrow + ks * 32);
      acc[ct] = __builtin_amdgcn_mfma_f32_16x16x32_bf16(a[ks], b, acc[ct], 0, 0, 0);
    }
  }
  int rbase = strip * 16 + g * 4;
#pragma unroll
  for (int ct = 0; ct < 8; ct++) {
    int col = ct * 16 + r16;
    float bv = (BR & 1) ? bias[col] : 0.f;
#pragma unroll
    for (int i = 0; i < 4; i++) {
      float v = acc[ct][i] + bv;
      if (BR & 2) v = fmaxf(v, 0.f);
      size_t idx = (size_t)(rbase + i) * 128 + col;
      Y[idx] = (__bf16)v;
      if constexpr (DUAL) Yf[idx] = v;
    }
  }
}

template<int BR, bool IN_BF16, bool DUAL>
__global__ __launch_bounds__(256) void k_mm128(const void* __restrict__ Xv, const float* __restrict__ W,
                                               const float* __restrict__ bias, __bf16* __restrict__ Y,
                                               float* __restrict__ Yf, int nrows) {
  __shared__ __bf16 wt[128][136];
  int tid = threadIdx.x;
  stage_wt(W, wt, tid);
  __syncthreads();
  int strip = blockIdx.x * 4 + (tid >> 6);
  if (strip * 16 >= nrows) return;
  mm_body<BR, IN_BF16, DUAL>(Xv, wt, bias, Y, Yf, strip, tid & 63);
}

// ---------- fused: blocks [0,MM1_BLOCKS) do mm1 (x@w1); rest do degree count ----------
__global__ __launch_bounds__(256) void k_mm1_count(const float* __restrict__ X, const float* __restrict__ W,
                                                   __bf16* __restrict__ Y,
                                                   const int* __restrict__ dstv, int* __restrict__ degi) {
  __shared__ __bf16 wt[128][136];
  int tid = threadIdx.x;
  if (blockIdx.x >= MM1_BLOCKS) {
    int e = (blockIdx.x - MM1_BLOCKS) * 256 + tid;
    if (e < NE) atomicAdd(&degi[dstv[e]], 1);
    return;
  }
  stage_wt(W, wt, tid);
  __syncthreads();
  int strip = blockIdx.x * 4 + (tid >> 6);
  if (strip * 16 >= NN) return;
  mm_body<0, false, false>(X, wt, nullptr, Y, nullptr, strip, tid & 63);
}

// ---------- task heads: bf16 [N,128] @ [128,50] -> y[t][n][c] fp32 ----------
__global__ __launch_bounds__(256) void k_head(const __bf16* __restrict__ H, const float* __restrict__ TW,
                                              const float* __restrict__ TB, float* __restrict__ Y) {
  __shared__ __bf16 wt[64][136];  // wt[o][k] = task_w[o/10][k][o%10], o<50; else 0
  int tid = threadIdx.x;
  for (int i = tid; i < 8192; i += 256) {
    int o = i >> 7, k = i & 127;
    float v = 0.f;
    if (o < 50) v = TW[(o / 10) * 1280 + k * 10 + (o % 10)];
    wt[o][k] = (__bf16)v;
  }
  __syncthreads();
  int lane = tid & 63;
  int strip = blockIdx.x * 4 + (tid >> 6);
  if (strip * 16 >= NN) return;
  int r16 = lane & 15, g = lane >> 4;
  const __bf16* xb = H + (size_t)(strip * 16 + r16) * 128 + g * 8;
  bf16x8 a[4];
#pragma unroll
  for (int ks = 0; ks < 4; ks++) a[ks] = *(const bf16x8*)(xb + ks * 32);
  f32x4 acc[4];
#pragma unroll
  for (int ct = 0; ct < 4; ct++) acc[ct] = (f32x4){0.f, 0.f, 0.f, 0.f};
#pragma unroll
  for (int ct = 0; ct < 4; ct++) {
    const __bf16* wrow = &wt[ct * 16 + r16][g * 8];
#pragma unroll
    for (int ks = 0; ks < 4; ks++) {
      bf16x8 b = *(const bf16x8*)(wrow + ks * 32);
      acc[ct] = __builtin_amdgcn_mfma_f32_16x16x32_bf16(a[ks], b, acc[ct], 0, 0, 0);
    }
  }
  int rbase = strip * 16 + g * 4;
#pragma unroll
  for (int ct = 0; ct < 4; ct++) {
    int o = ct * 16 + r16;
    if (o < 50) {
      int t = o / 10, c = o % 10;
      float tb = TB[o];
#pragma unroll
      for (int i = 0; i < 4; i++) {
        Y[(size_t)t * (NN * 10) + (size_t)(rbase + i) * 10 + c] = acc[ct][i] + tb;
      }
    }
  }
}

// ---------- one 8-edge padded step (round-6 form) ----------
__device__ __forceinline__ void edge8(const int2* __restrict__ edg, int i, const unsigned* __restrict__ T,
                                      int lane, float& ax, float& ay) {
  const int4* ep = (const int4*)(edg + i);
  int4 p0 = ep[0], p1 = ep[1], p2 = ep[2], p3 = ep[3];
  unsigned v0 = T[p0.x * 64 + lane];
  unsigned v1 = T[p0.z * 64 + lane];
  unsigned v2 = T[p1.x * 64 + lane];
  unsigned v3 = T[p1.z * 64 + lane];
  unsigned v4 = T[p2.x * 64 + lane];
  unsigned v5 = T[p2.z * 64 + lane];
  unsigned v6 = T[p3.x * 64 + lane];
  unsigned v7 = T[p3.z * 64 + lane];
  float w0 = __int_as_float(p0.y), w1 = __int_as_float(p0.w);
  float w2 = __int_as_float(p1.y), w3 = __int_as_float(p1.w);
  float w4 = __int_as_float(p2.y), w5 = __int_as_float(p2.w);
  float w6 = __int_as_float(p3.y), w7 = __int_as_float(p3.w);
  ax = fmaf(__uint_as_float(v0 << 16), w0, ax); ay = fmaf(__uint_as_float(v0 & 0xffff0000u), w0, ay);
  ax = fmaf(__uint_as_float(v1 << 16), w1, ax); ay = fmaf(__uint_as_float(v1 & 0xffff0000u), w1, ay);
  ax = fmaf(__uint_as_float(v2 << 16), w2, ax); ay = fmaf(__uint_as_float(v2 & 0xffff0000u), w2, ay);
  ax = fmaf(__uint_as_float(v3 << 16), w3, ax); ay = fmaf(__uint_as_float(v3 & 0xffff0000u), w3, ay);
  ax = fmaf(__uint_as_float(v4 << 16), w4, ax); ay = fmaf(__uint_as_float(v4 & 0xffff0000u), w4, ay);
  ax = fmaf(__uint_as_float(v5 << 16), w5, ax); ay = fmaf(__uint_as_float(v5 & 0xffff0000u), w5, ay);
  ax = fmaf(__uint_as_float(v6 << 16), w6, ax); ay = fmaf(__uint_as_float(v6 & 0xffff0000u), w6, ay);
  ax = fmaf(__uint_as_float(v7 << 16), w7, ax); ay = fmaf(__uint_as_float(v7 & 0xffff0000u), w7, ay);
}

// ---------- CSR pull aggregation: TWO nodes per wave, fixed-stride rows ----------
__global__ __launch_bounds__(256) void k_agg(const unsigned* __restrict__ T, const int* __restrict__ degi,
                                             const int2* __restrict__ edg, const float* __restrict__ dinv,
                                             const float* __restrict__ bias, unsigned* __restrict__ H) {
  int pair = blockIdx.x * 4 + (threadIdx.x >> 6);
  int nA = pair * 2, nB = nA + 1;  // NN even, grid covers exactly
  int lane = threadIdx.x & 63;
  float2 b = ((const float2*)bias)[lane];
  float diA = dinv[nA], diB = dinv[nB];
  unsigned tA = T[(size_t)nA * 64 + lane];
  unsigned tB = T[(size_t)nB * 64 + lane];
  float axA = __uint_as_float(tA << 16) * (diA * diA);
  float ayA = __uint_as_float(tA & 0xffff0000u) * (diA * diA);
  float axB = __uint_as_float(tB << 16) * (diB * diB);
  float ayB = __uint_as_float(tB & 0xffff0000u) * (diB * diB);
  int iA = nA * STRIDE, eA = iA + ((degi[nA] + 7) & ~7);
  int iB = nB * STRIDE, eB = iB + ((degi[nB] + 7) & ~7);
  while (iA < eA && iB < eB) {  // paired: 16 gathers + 8 edge-vec loads in flight
    edge8(edg, iA, T, lane, axA, ayA);
    edge8(edg, iB, T, lane, axB, ayB);
    iA += 8; iB += 8;
  }
  for (; iA < eA; iA += 8) edge8(edg, iA, T, lane, axA, ayA);
  for (; iB < eB; iB += 8) edge8(edg, iB, T, lane, axB, ayB);
  H[(size_t)nA * 64 + lane] = pack2bf16(fmaxf(axA + b.x, 0.f), fmaxf(ayA + b.y, 0.f));
  H[(size_t)nB * 64 + lane] = pack2bf16(fmaxf(axB + b.x, 0.f), fmaxf(ayB + b.y, 0.f));
}

extern "C" void kernel_launch(void* const* d_in, const int* in_sizes, int n_in,
                              void* d_out, int out_size, void* d_ws, size_t ws_size,
                              hipStream_t stream) {
  (void)in_sizes; (void)n_in; (void)out_size; (void)ws_size;
  const float* x   = (const float*)d_in[0];
  const int*   ei  = (const int*)d_in[1];
  const float* w1  = (const float*)d_in[2];
  const float* b1  = (const float*)d_in[3];
  const float* w2  = (const float*)d_in[4];
  const float* b2  = (const float*)d_in[5];
  const float* fw1 = (const float*)d_in[6];
  const float* fb1 = (const float*)d_in[7];
  const float* fw2 = (const float*)d_in[8];
  const float* fb2 = (const float*)d_in[9];
  const float* tw  = (const float*)d_in[10];
  const float* tb  = (const float*)d_in[11];
  const int* srcv = ei;
  const int* dstv = ei + NE;

  char* wsb = (char*)d_ws;
  __bf16* bufT = (__bf16*)(wsb + 0);         // 12,800,000 B  [N,128] bf16
  __bf16* hbf  = (__bf16*)(wsb + 12800000);  // 12,800,000 B  [N,128] bf16
  int*    degi = (int*)(wsb + 25600000);     //    200,000 B
  int*    cur  = (int*)(wsb + 25800192);     //    200,000 B
  float*  dinv = (float*)(wsb + 26000640);   //    200,000 B
  int2*   edg  = (int2*)(wsb + 26201088);    // 25,600,000 B (fixed stride 64/node)
  // total ~52 MB of 256 MB ws

  float* y_out = (float*)d_out;              // [5,50000,10]
  float* feat  = (float*)d_out + 2500000;    // [50000,128] feature_x fp32

  // --- CSR build (no scans; mm1 fused with count) ---
  k_zero<<<196, 256, 0, stream>>>(degi);
  k_mm1_count<<<MM1_BLOCKS + (NE + 255) / 256, 256, 0, stream>>>(x, w1, bufT, dstv, degi);
  k_prep<<<196, 256, 0, stream>>>(degi, cur, dinv, edg);
  k_fill<<<(NE + 255) / 256, 256, 0, stream>>>(srcv, dstv, cur, edg, dinv);

  // --- GCN layer 1 aggregation ---
  k_agg<<<6250, 256, 0, stream>>>((const unsigned*)bufT, degi, edg, dinv, b1, (unsigned*)hbf);
  // --- GCN layer 2 ---
  k_mm128<0, true, false><<<782, 256, 0, stream>>>(hbf, w2, nullptr, bufT, nullptr, NN);
  k_agg<<<6250, 256, 0, stream>>>((const unsigned*)bufT, degi, edg, dinv, b2, (unsigned*)hbf);
  // --- fc1: feature_x (fp32 to d_out, bf16 in-place for fc2) ---
  k_mm128<3, true, true><<<782, 256, 0, stream>>>(hbf, fw1, fb1, hbf, feat, NN);
  // --- fc2 ---
  k_mm128<3, true, false><<<782, 256, 0, stream>>>(hbf, fw2, fb2, bufT, nullptr, NN);
  // --- heads ---
  k_head<<<782, 256, 0, stream>>>(bufT, tw, tb, y_out);
}

// Round 10
// 179.315 us; speedup vs baseline: 1.6222x; 1.0183x over previous
//
#include <hip/hip_runtime.h>
#include <hip/hip_bf16.h>

#define NN 50000
#define NE 600000
#define MM1_BLOCKS 782
#define STRIDE 64  // fixed edge slots per node; P(deg>=64) ~ 1e-30 for Poisson(12)

typedef __attribute__((ext_vector_type(4))) float f32x4;
typedef __attribute__((ext_vector_type(8))) __bf16 bf16x8;

__device__ __forceinline__ unsigned pack2bf16(float x, float y) {
  __bf16 lo = (__bf16)x, hi = (__bf16)y;
  unsigned short ul = __builtin_bit_cast(unsigned short, lo);
  unsigned short uh = __builtin_bit_cast(unsigned short, hi);
  return (unsigned)ul | ((unsigned)uh << 16);
}

// ---------- CSR build (fixed stride, no scans) ----------
__global__ void k_zero(int* __restrict__ degi) {
  int i = blockIdx.x * 256 + threadIdx.x;
  if (i < NN) degi[i] = 0;
}

// per-node: cursor, dinv, zero pad slots [deg, pad8(deg))
__global__ void k_prep(const int* __restrict__ degi, int* __restrict__ cur,
                       float* __restrict__ dinv, int2* __restrict__ edg) {
  int n = blockIdx.x * 256 + threadIdx.x;
  if (n < NN) {
    int d = degi[n];
    int base = n * STRIDE;
    cur[n] = base;
    dinv[n] = rsqrtf((float)(d + 1));  // +1 self-loop; always > 0
    int pe = base + ((d + 7) & ~7);
    for (int j = base + d; j < pe; j++) edg[j] = make_int2(0, 0);  // weight-0: inert
  }
}

__global__ void k_fill(const int* __restrict__ srcv, const int* __restrict__ dstv,
                       int* __restrict__ cur, int2* __restrict__ edg, const float* __restrict__ dinv) {
  int e = blockIdx.x * 256 + threadIdx.x;
  if (e < NE) {
    int s = srcv[e], d = dstv[e];
    int p = atomicAdd(&cur[d], 1);
    edg[p] = make_int2(s, __float_as_int(dinv[s] * dinv[d]));
  }
}

// ---------- conflict-free W^T staging: wt[j][k] = W[k][j] ----------
__device__ __forceinline__ void stage_wt(const float* __restrict__ W, __bf16 (*wt)[136], int tid) {
  int j = tid & 127;
  int hi = tid >> 7;  // 0 or 1
#pragma unroll 4
  for (int it = 0; it < 32; ++it) {
    int kp = ((it << 1) + hi + (j >> 3)) & 63;
    float w0 = W[(kp * 2) * 128 + j];
    float w1 = W[(kp * 2 + 1) * 128 + j];
    *(unsigned*)(&wt[j][kp * 2]) = pack2bf16(w0, w1);
  }
}

// ---------- mm body: [16-row strip] @ [128,128] via MFMA ----------
template<int BR, bool IN_BF16, bool DUAL>
__device__ __forceinline__ void mm_body(const void* __restrict__ Xv, const __bf16 (*wt)[136],
                                        const float* __restrict__ bias, __bf16* __restrict__ Y,
                                        float* __restrict__ Yf, int strip, int lane) {
  int r16 = lane & 15, g = lane >> 4;
  bf16x8 a[4];
  if constexpr (IN_BF16) {
    const __bf16* xb = (const __bf16*)Xv + (size_t)(strip * 16 + r16) * 128 + g * 8;
#pragma unroll
    for (int ks = 0; ks < 4; ks++) a[ks] = *(const bf16x8*)(xb + ks * 32);
  } else {
    const float* xb = (const float*)Xv + (size_t)(strip * 16 + r16) * 128 + g * 8;
#pragma unroll
    for (int ks = 0; ks < 4; ks++) {
      f32x4 x0 = *(const f32x4*)(xb + ks * 32);
      f32x4 x1 = *(const f32x4*)(xb + ks * 32 + 4);
      bf16x8 v;
      v[0] = (__bf16)x0.x; v[1] = (__bf16)x0.y; v[2] = (__bf16)x0.z; v[3] = (__bf16)x0.w;
      v[4] = (__bf16)x1.x; v[5] = (__bf16)x1.y; v[6] = (__bf16)x1.z; v[7] = (__bf16)x1.w;
      a[ks] = v;
    }
  }
  f32x4 acc[8];
#pragma unroll
  for (int ct = 0; ct < 8; ct++) acc[ct] = (f32x4){0.f, 0.f, 0.f, 0.f};
#pragma unroll
  for (int ct = 0; ct < 8; ct++) {
    const __bf16* wrow = &wt[ct * 16 + r16][g * 8];
#pragma unroll
    for (int ks = 0; ks < 4; ks++) {
      bf16x8 b = *(const bf16x8*)(wrow + ks * 32);
      acc[ct] = __builtin_amdgcn_mfma_f32_16x16x32_bf16(a[ks], b, acc[ct], 0, 0, 0);
    }
  }
  int rbase = strip * 16 + g * 4;
#pragma unroll
  for (int ct = 0; ct < 8; ct++) {
    int col = ct * 16 + r16;
    float bv = (BR & 1) ? bias[col] : 0.f;
#pragma unroll
    for (int i = 0; i < 4; i++) {
      float v = acc[ct][i] + bv;
      if (BR & 2) v = fmaxf(v, 0.f);
      size_t idx = (size_t)(rbase + i) * 128 + col;
      Y[idx] = (__bf16)v;
      if constexpr (DUAL) Yf[idx] = v;
    }
  }
}

template<int BR, bool IN_BF16, bool DUAL>
__global__ __launch_bounds__(256) void k_mm128(const void* __restrict__ Xv, const float* __restrict__ W,
                                               const float* __restrict__ bias, __bf16* __restrict__ Y,
                                               float* __restrict__ Yf, int nrows) {
  __shared__ __bf16 wt[128][136];
  int tid = threadIdx.x;
  stage_wt(W, wt, tid);
  __syncthreads();
  int strip = blockIdx.x * 4 + (tid >> 6);
  if (strip * 16 >= nrows) return;
  mm_body<BR, IN_BF16, DUAL>(Xv, wt, bias, Y, Yf, strip, tid & 63);
}

// ---------- fused: blocks [0,MM1_BLOCKS) do mm1 (x@w1); rest do degree count ----------
__global__ __launch_bounds__(256) void k_mm1_count(const float* __restrict__ X, const float* __restrict__ W,
                                                   __bf16* __restrict__ Y,
                                                   const int* __restrict__ dstv, int* __restrict__ degi) {
  __shared__ __bf16 wt[128][136];
  int tid = threadIdx.x;
  if (blockIdx.x >= MM1_BLOCKS) {
    int e = (blockIdx.x - MM1_BLOCKS) * 256 + tid;
    if (e < NE) atomicAdd(&degi[dstv[e]], 1);
    return;
  }
  stage_wt(W, wt, tid);
  __syncthreads();
  int strip = blockIdx.x * 4 + (tid >> 6);
  if (strip * 16 >= NN) return;
  mm_body<0, false, false>(X, wt, nullptr, Y, nullptr, strip, tid & 63);
}

// ---------- fused MLP tail: fc1 -> feature_x, fc2, heads (row-local; conflict-free staging) ----------
__global__ __launch_bounds__(256) void k_mlp(const __bf16* __restrict__ H,
                                             const float* __restrict__ fw1, const float* __restrict__ fb1,
                                             const float* __restrict__ fw2, const float* __restrict__ fb2,
                                             const float* __restrict__ tw, const float* __restrict__ tb,
                                             float* __restrict__ feat, float* __restrict__ y) {
  __shared__ __bf16 wS[128][136];  // re-staged per phase: fw1^T, fw2^T, head w
  __shared__ __bf16 stg[64][136];  // per-block 64-row activation staging (wave-private rows)
  int tid = threadIdx.x;
  stage_wt(fw1, wS, tid);
  __syncthreads();
  int lane = tid & 63, wv = tid >> 6;
  int strip = blockIdx.x * 4 + wv;
  bool act = (strip * 16 < NN);
  int r16 = lane & 15, g = lane >> 4;
  int lrow = wv * 16;
  f32x4 acc[8];
  // ---- fc1 ----
  if (act) {
    const __bf16* xb = H + (size_t)(strip * 16 + r16) * 128 + g * 8;
    bf16x8 a[4];
#pragma unroll
    for (int ks = 0; ks < 4; ks++) a[ks] = *(const bf16x8*)(xb + ks * 32);
#pragma unroll
    for (int ct = 0; ct < 8; ct++) acc[ct] = (f32x4){0.f, 0.f, 0.f, 0.f};
#pragma unroll
    for (int ct = 0; ct < 8; ct++) {
      const __bf16* wrow = &wS[ct * 16 + r16][g * 8];
#pragma unroll
      for (int ks = 0; ks < 4; ks++)
        acc[ct] = __builtin_amdgcn_mfma_f32_16x16x32_bf16(a[ks], *(const bf16x8*)(wrow + ks * 32), acc[ct], 0, 0, 0);
    }
    int rbase = strip * 16 + g * 4;
#pragma unroll
    for (int ct = 0; ct < 8; ct++) {
      int col = ct * 16 + r16;
      float bv = fb1[col];
#pragma unroll
      for (int i = 0; i < 4; i++) {
        float v = fmaxf(acc[ct][i] + bv, 0.f);
        feat[(size_t)(rbase + i) * 128 + col] = v;   // feature_x output (fp32)
        stg[lrow + g * 4 + i][col] = (__bf16)v;      // fc2 input
      }
    }
  }
  __syncthreads();
  stage_wt(fw2, wS, tid);
  __syncthreads();
  // ---- fc2 (wave-private rows of stg) ----
  if (act) {
    bf16x8 a[4];
#pragma unroll
    for (int ks = 0; ks < 4; ks++) a[ks] = *(const bf16x8*)(&stg[lrow + r16][g * 8 + ks * 32]);
#pragma unroll
    for (int ct = 0; ct < 8; ct++) acc[ct] = (f32x4){0.f, 0.f, 0.f, 0.f};
#pragma unroll
    for (int ct = 0; ct < 8; ct++) {
      const __bf16* wrow = &wS[ct * 16 + r16][g * 8];
#pragma unroll
      for (int ks = 0; ks < 4; ks++)
        acc[ct] = __builtin_amdgcn_mfma_f32_16x16x32_bf16(a[ks], *(const bf16x8*)(wrow + ks * 32), acc[ct], 0, 0, 0);
    }
#pragma unroll
    for (int ct = 0; ct < 8; ct++) {
      int col = ct * 16 + r16;
      float bv = fb2[col];
#pragma unroll
      for (int i = 0; i < 4; i++) stg[lrow + g * 4 + i][col] = (__bf16)fmaxf(acc[ct][i] + bv, 0.f);
    }
  }
  __syncthreads();
  // head weights: wS[o][k] = task_w[o/10][k][o%10], o<50 (consecutive tid -> consecutive k: <=2-way)
  for (int i = tid; i < 8192; i += 256) {
    int o = i >> 7, k = i & 127;
    float v = (o < 50) ? tw[(o / 10) * 1280 + k * 10 + (o % 10)] : 0.f;
    wS[o][k] = (__bf16)v;
  }
  __syncthreads();
  // ---- heads ----
  if (act) {
    bf16x8 a[4];
#pragma unroll
    for (int ks = 0; ks < 4; ks++) a[ks] = *(const bf16x8*)(&stg[lrow + r16][g * 8 + ks * 32]);
    f32x4 hacc[4];
#pragma unroll
    for (int ct = 0; ct < 4; ct++) hacc[ct] = (f32x4){0.f, 0.f, 0.f, 0.f};
#pragma unroll
    for (int ct = 0; ct < 4; ct++) {
      const __bf16* wrow = &wS[ct * 16 + r16][g * 8];
#pragma unroll
      for (int ks = 0; ks < 4; ks++)
        hacc[ct] = __builtin_amdgcn_mfma_f32_16x16x32_bf16(a[ks], *(const bf16x8*)(wrow + ks * 32), hacc[ct], 0, 0, 0);
    }
    int rbase = strip * 16 + g * 4;
#pragma unroll
    for (int ct = 0; ct < 4; ct++) {
      int o = ct * 16 + r16;
      if (o < 50) {
        int t = o / 10, c = o % 10;
        float tbv = tb[o];
#pragma unroll
        for (int i = 0; i < 4; i++)
          y[(size_t)t * (NN * 10) + (size_t)(rbase + i) * 10 + c] = hacc[ct][i] + tbv;
      }
    }
  }
}

// ---------- one 8-edge padded step ----------
__device__ __forceinline__ void edge8(const int2* __restrict__ edg, int i, const unsigned* __restrict__ T,
                                      int lane, float& ax, float& ay) {
  const int4* ep = (const int4*)(edg + i);
  int4 p0 = ep[0], p1 = ep[1], p2 = ep[2], p3 = ep[3];
  unsigned v0 = T[p0.x * 64 + lane];
  unsigned v1 = T[p0.z * 64 + lane];
  unsigned v2 = T[p1.x * 64 + lane];
  unsigned v3 = T[p1.z * 64 + lane];
  unsigned v4 = T[p2.x * 64 + lane];
  unsigned v5 = T[p2.z * 64 + lane];
  unsigned v6 = T[p3.x * 64 + lane];
  unsigned v7 = T[p3.z * 64 + lane];
  float w0 = __int_as_float(p0.y), w1 = __int_as_float(p0.w);
  float w2 = __int_as_float(p1.y), w3 = __int_as_float(p1.w);
  float w4 = __int_as_float(p2.y), w5 = __int_as_float(p2.w);
  float w6 = __int_as_float(p3.y), w7 = __int_as_float(p3.w);
  ax = fmaf(__uint_as_float(v0 << 16), w0, ax); ay = fmaf(__uint_as_float(v0 & 0xffff0000u), w0, ay);
  ax = fmaf(__uint_as_float(v1 << 16), w1, ax); ay = fmaf(__uint_as_float(v1 & 0xffff0000u), w1, ay);
  ax = fmaf(__uint_as_float(v2 << 16), w2, ax); ay = fmaf(__uint_as_float(v2 & 0xffff0000u), w2, ay);
  ax = fmaf(__uint_as_float(v3 << 16), w3, ax); ay = fmaf(__uint_as_float(v3 & 0xffff0000u), w3, ay);
  ax = fmaf(__uint_as_float(v4 << 16), w4, ax); ay = fmaf(__uint_as_float(v4 & 0xffff0000u), w4, ay);
  ax = fmaf(__uint_as_float(v5 << 16), w5, ax); ay = fmaf(__uint_as_float(v5 & 0xffff0000u), w5, ay);
  ax = fmaf(__uint_as_float(v6 << 16), w6, ax); ay = fmaf(__uint_as_float(v6 & 0xffff0000u), w6, ay);
  ax = fmaf(__uint_as_float(v7 << 16), w7, ax); ay = fmaf(__uint_as_float(v7 & 0xffff0000u), w7, ay);
}

// ---------- CSR pull aggregation: TWO nodes per wave, fixed-stride rows ----------
__global__ __launch_bounds__(256) void k_agg(const unsigned* __restrict__ T, const int* __restrict__ degi,
                                             const int2* __restrict__ edg, const float* __restrict__ dinv,
                                             const float* __restrict__ bias, unsigned* __restrict__ H) {
  int pair = blockIdx.x * 4 + (threadIdx.x >> 6);
  int nA = pair * 2, nB = nA + 1;  // NN even, grid covers exactly
  int lane = threadIdx.x & 63;
  float2 b = ((const float2*)bias)[lane];
  float diA = dinv[nA], diB = dinv[nB];
  unsigned tA = T[(size_t)nA * 64 + lane];
  unsigned tB = T[(size_t)nB * 64 + lane];
  float axA = __uint_as_float(tA << 16) * (diA * diA);
  float ayA = __uint_as_float(tA & 0xffff0000u) * (diA * diA);
  float axB = __uint_as_float(tB << 16) * (diB * diB);
  float ayB = __uint_as_float(tB & 0xffff0000u) * (diB * diB);
  int iA = nA * STRIDE, eA = iA + ((degi[nA] + 7) & ~7);
  int iB = nB * STRIDE, eB = iB + ((degi[nB] + 7) & ~7);
  while (iA < eA && iB < eB) {  // paired: 16 gathers + 8 edge-vec loads in flight
    edge8(edg, iA, T, lane, axA, ayA);
    edge8(edg, iB, T, lane, axB, ayB);
    iA += 8; iB += 8;
  }
  for (; iA < eA; iA += 8) edge8(edg, iA, T, lane, axA, ayA);
  for (; iB < eB; iB += 8) edge8(edg, iB, T, lane, axB, ayB);
  H[(size_t)nA * 64 + lane] = pack2bf16(fmaxf(axA + b.x, 0.f), fmaxf(ayA + b.y, 0.f));
  H[(size_t)nB * 64 + lane] = pack2bf16(fmaxf(axB + b.x, 0.f), fmaxf(ayB + b.y, 0.f));
}

extern "C" void kernel_launch(void* const* d_in, const int* in_sizes, int n_in,
                              void* d_out, int out_size, void* d_ws, size_t ws_size,
                              hipStream_t stream) {
  (void)in_sizes; (void)n_in; (void)out_size; (void)ws_size;
  const float* x   = (const float*)d_in[0];
  const int*   ei  = (const int*)d_in[1];
  const float* w1  = (const float*)d_in[2];
  const float* b1  = (const float*)d_in[3];
  const float* w2  = (const float*)d_in[4];
  const float* b2  = (const float*)d_in[5];
  const float* fw1 = (const float*)d_in[6];
  const float* fb1 = (const float*)d_in[7];
  const float* fw2 = (const float*)d_in[8];
  const float* fb2 = (const float*)d_in[9];
  const float* tw  = (const float*)d_in[10];
  const float* tb  = (const float*)d_in[11];
  const int* srcv = ei;
  const int* dstv = ei + NE;

  char* wsb = (char*)d_ws;
  __bf16* bufT = (__bf16*)(wsb + 0);         // 12,800,000 B  [N,128] bf16
  __bf16* hbf  = (__bf16*)(wsb + 12800000);  // 12,800,000 B  [N,128] bf16
  int*    degi = (int*)(wsb + 25600000);     //    200,000 B
  int*    cur  = (int*)(wsb + 25800192);     //    200,000 B
  float*  dinv = (float*)(wsb + 26000640);   //    200,000 B
  int2*   edg  = (int2*)(wsb + 26201088);    // 25,600,000 B (fixed stride 64/node)
  // total ~52 MB of 256 MB ws

  float* y_out = (float*)d_out;              // [5,50000,10]
  float* feat  = (float*)d_out + 2500000;    // [50000,128] feature_x fp32

  // --- CSR build (no scans; mm1 fused with count) ---
  k_zero<<<196, 256, 0, stream>>>(degi);
  k_mm1_count<<<MM1_BLOCKS + (NE + 255) / 256, 256, 0, stream>>>(x, w1, bufT, dstv, degi);
  k_prep<<<196, 256, 0, stream>>>(degi, cur, dinv, edg);
  k_fill<<<(NE + 255) / 256, 256, 0, stream>>>(srcv, dstv, cur, edg, dinv);

  // --- GCN layer 1 aggregation ---
  k_agg<<<6250, 256, 0, stream>>>((const unsigned*)bufT, degi, edg, dinv, b1, (unsigned*)hbf);
  // --- GCN layer 2 ---
  k_mm128<0, true, false><<<782, 256, 0, stream>>>(hbf, w2, nullptr, bufT, nullptr, NN);
  k_agg<<<6250, 256, 0, stream>>>((const unsigned*)bufT, degi, edg, dinv, b2, (unsigned*)hbf);
  // --- fused fc1 + fc2 + heads ---
  k_mlp<<<782, 256, 0, stream>>>(hbf, fw1, fb1, fw2, fb2, tw, tb, feat, y_out);
}

// Round 11
// 175.964 us; speedup vs baseline: 1.6531x; 1.0190x over previous
//
#include <hip/hip_runtime.h>
#include <hip/hip_bf16.h>

#define NN 50000
#define NE 600000
#define MM1_BLOCKS 1564
#define STRIDE 64  // fixed edge slots per node; P(deg>=64) ~ 1e-30 for Poisson(12)

typedef __attribute__((ext_vector_type(4))) float f32x4;
typedef __attribute__((ext_vector_type(8))) __bf16 bf16x8;

__device__ __forceinline__ unsigned pack2bf16(float x, float y) {
  __bf16 lo = (__bf16)x, hi = (__bf16)y;
  unsigned short ul = __builtin_bit_cast(unsigned short, lo);
  unsigned short uh = __builtin_bit_cast(unsigned short, hi);
  return (unsigned)ul | ((unsigned)uh << 16);
}

// ---------- CSR build (fixed stride, no scans) ----------
__global__ void k_zero(int* __restrict__ degi) {
  int i = blockIdx.x * 256 + threadIdx.x;
  if (i < NN) degi[i] = 0;
}

__global__ void k_prep(const int* __restrict__ degi, int* __restrict__ cur,
                       float* __restrict__ dinv, int2* __restrict__ edg) {
  int n = blockIdx.x * 256 + threadIdx.x;
  if (n < NN) {
    int d = degi[n];
    int base = n * STRIDE;
    cur[n] = base;
    dinv[n] = rsqrtf((float)(d + 1));  // +1 self-loop; always > 0
    int pe = base + ((d + 7) & ~7);
    for (int j = base + d; j < pe; j++) edg[j] = make_int2(0, 0);  // weight-0: inert
  }
}

__global__ void k_fill(const int* __restrict__ srcv, const int* __restrict__ dstv,
                       int* __restrict__ cur, int2* __restrict__ edg, const float* __restrict__ dinv) {
  int e = blockIdx.x * 256 + threadIdx.x;
  if (e < NE) {
    int s = srcv[e], d = dstv[e];
    int p = atomicAdd(&cur[d], 1);
    edg[p] = make_int2(s, __float_as_int(dinv[s] * dinv[d]));
  }
}

// ---------- conflict-free half-W^T staging: wt[j][k] = W[k][colbase+j], j<64 ----------
// 32 independent loads/thread, fully unrolled; diagonal kp remap -> <=2-way LDS banks (free).
__device__ __forceinline__ void stage_wt64(const float* __restrict__ W, __bf16 (*wt)[136],
                                           int tid, int colbase) {
  int j = tid & 63;
  int kh = tid >> 6;  // 0..3
#pragma unroll
  for (int it = 0; it < 16; ++it) {
    int kp = ((it << 2) + kh + (j >> 3)) & 63;
    float w0 = W[(kp * 2) * 128 + colbase + j];
    float w1 = W[(kp * 2 + 1) * 128 + colbase + j];
    *(unsigned*)(&wt[j][kp * 2]) = pack2bf16(w0, w1);
  }
}

// ---------- mm body: 16-row strip x 64-col half, K=128, bf16 MFMA ----------
template<int BR, bool IN_BF16, bool DUAL>
__device__ __forceinline__ void mm_body64(const void* __restrict__ Xv, const __bf16 (*wt)[136],
                                          const float* __restrict__ bias, __bf16* __restrict__ Y,
                                          float* __restrict__ Yf, int strip, int lane, int colbase) {
  int r16 = lane & 15, g = lane >> 4;
  bf16x8 a[4];
  if constexpr (IN_BF16) {
    const __bf16* xb = (const __bf16*)Xv + (size_t)(strip * 16 + r16) * 128 + g * 8;
#pragma unroll
    for (int ks = 0; ks < 4; ks++) a[ks] = *(const bf16x8*)(xb + ks * 32);
  } else {
    const float* xb = (const float*)Xv + (size_t)(strip * 16 + r16) * 128 + g * 8;
#pragma unroll
    for (int ks = 0; ks < 4; ks++) {
      f32x4 x0 = *(const f32x4*)(xb + ks * 32);
      f32x4 x1 = *(const f32x4*)(xb + ks * 32 + 4);
      bf16x8 v;
      v[0] = (__bf16)x0.x; v[1] = (__bf16)x0.y; v[2] = (__bf16)x0.z; v[3] = (__bf16)x0.w;
      v[4] = (__bf16)x1.x; v[5] = (__bf16)x1.y; v[6] = (__bf16)x1.z; v[7] = (__bf16)x1.w;
      a[ks] = v;
    }
  }
  f32x4 acc[4];
#pragma unroll
  for (int ct = 0; ct < 4; ct++) acc[ct] = (f32x4){0.f, 0.f, 0.f, 0.f};
#pragma unroll
  for (int ct = 0; ct < 4; ct++) {
    const __bf16* wrow = &wt[ct * 16 + r16][g * 8];
#pragma unroll
    for (int ks = 0; ks < 4; ks++) {
      bf16x8 b = *(const bf16x8*)(wrow + ks * 32);
      acc[ct] = __builtin_amdgcn_mfma_f32_16x16x32_bf16(a[ks], b, acc[ct], 0, 0, 0);
    }
  }
  int rbase = strip * 16 + g * 4;
#pragma unroll
  for (int ct = 0; ct < 4; ct++) {
    int col = colbase + ct * 16 + r16;
    float bv = (BR & 1) ? bias[col] : 0.f;
#pragma unroll
    for (int i = 0; i < 4; i++) {
      float v = acc[ct][i] + bv;
      if (BR & 2) v = fmaxf(v, 0.f);
      size_t idx = (size_t)(rbase + i) * 128 + col;
      Y[idx] = (__bf16)v;
      if constexpr (DUAL) Yf[idx] = v;
    }
  }
}

// column-split mm: 1564 blocks, block b -> strips (b>>1)*4+wv, cols (b&1)*64..+63
template<int BR, bool IN_BF16, bool DUAL>
__global__ __launch_bounds__(256) void k_mm64(const void* __restrict__ Xv, const float* __restrict__ W,
                                              const float* __restrict__ bias, __bf16* __restrict__ Y,
                                              float* __restrict__ Yf, int nrows) {
  __shared__ __bf16 wt[64][136];
  int tid = threadIdx.x;
  int colbase = (blockIdx.x & 1) << 6;
  stage_wt64(W, wt, tid, colbase);
  __syncthreads();
  int strip = (blockIdx.x >> 1) * 4 + (tid >> 6);
  if (strip * 16 >= nrows) return;
  mm_body64<BR, IN_BF16, DUAL>(Xv, wt, bias, Y, Yf, strip, tid & 63, colbase);
}

// ---------- fused: blocks [0,MM1_BLOCKS) do mm1 halves; rest do degree count ----------
__global__ __launch_bounds__(256) void k_mm1_count(const float* __restrict__ X, const float* __restrict__ W,
                                                   __bf16* __restrict__ Y,
                                                   const int* __restrict__ dstv, int* __restrict__ degi) {
  __shared__ __bf16 wt[64][136];
  int tid = threadIdx.x;
  if (blockIdx.x >= MM1_BLOCKS) {
    int e = (blockIdx.x - MM1_BLOCKS) * 256 + tid;
    if (e < NE) atomicAdd(&degi[dstv[e]], 1);
    return;
  }
  int colbase = (blockIdx.x & 1) << 6;
  stage_wt64(W, wt, tid, colbase);
  __syncthreads();
  int strip = (blockIdx.x >> 1) * 4 + (tid >> 6);
  if (strip * 16 >= NN) return;
  mm_body64<0, false, false>(X, wt, nullptr, Y, nullptr, strip, tid & 63, colbase);
}

// ---------- task heads: bf16 [N,128] @ [128,50] -> y[t][n][c] fp32 ----------
__global__ __launch_bounds__(256) void k_head(const __bf16* __restrict__ H, const float* __restrict__ TW,
                                              const float* __restrict__ TB, float* __restrict__ Y) {
  __shared__ __bf16 wt[64][136];  // wt[o][k] = task_w[o/10][k][o%10], o<50; else 0
  int tid = threadIdx.x;
#pragma unroll
  for (int it = 0; it < 32; it++) {
    int i = it * 256 + tid;
    int o = i >> 7, k = i & 127;
    float v = (o < 50) ? TW[(o / 10) * 1280 + k * 10 + (o % 10)] : 0.f;
    wt[o][k] = (__bf16)v;
  }
  __syncthreads();
  int lane = tid & 63;
  int strip = blockIdx.x * 4 + (tid >> 6);
  if (strip * 16 >= NN) return;
  int r16 = lane & 15, g = lane >> 4;
  const __bf16* xb = H + (size_t)(strip * 16 + r16) * 128 + g * 8;
  bf16x8 a[4];
#pragma unroll
  for (int ks = 0; ks < 4; ks++) a[ks] = *(const bf16x8*)(xb + ks * 32);
  f32x4 acc[4];
#pragma unroll
  for (int ct = 0; ct < 4; ct++) acc[ct] = (f32x4){0.f, 0.f, 0.f, 0.f};
#pragma unroll
  for (int ct = 0; ct < 4; ct++) {
    const __bf16* wrow = &wt[ct * 16 + r16][g * 8];
#pragma unroll
    for (int ks = 0; ks < 4; ks++) {
      bf16x8 b = *(const bf16x8*)(wrow + ks * 32);
      acc[ct] = __builtin_amdgcn_mfma_f32_16x16x32_bf16(a[ks], b, acc[ct], 0, 0, 0);
    }
  }
  int rbase = strip * 16 + g * 4;
#pragma unroll
  for (int ct = 0; ct < 4; ct++) {
    int o = ct * 16 + r16;
    if (o < 50) {
      int t = o / 10, c = o % 10;
      float tb = TB[o];
#pragma unroll
      for (int i = 0; i < 4; i++) {
        Y[(size_t)t * (NN * 10) + (size_t)(rbase + i) * 10 + c] = acc[ct][i] + tb;
      }
    }
  }
}

// ---------- one 8-edge padded step ----------
__device__ __forceinline__ void edge8(const int2* __restrict__ edg, int i, const unsigned* __restrict__ T,
                                      int lane, float& ax, float& ay) {
  const int4* ep = (const int4*)(edg + i);
  int4 p0 = ep[0], p1 = ep[1], p2 = ep[2], p3 = ep[3];
  unsigned v0 = T[p0.x * 64 + lane];
  unsigned v1 = T[p0.z * 64 + lane];
  unsigned v2 = T[p1.x * 64 + lane];
  unsigned v3 = T[p1.z * 64 + lane];
  unsigned v4 = T[p2.x * 64 + lane];
  unsigned v5 = T[p2.z * 64 + lane];
  unsigned v6 = T[p3.x * 64 + lane];
  unsigned v7 = T[p3.z * 64 + lane];
  float w0 = __int_as_float(p0.y), w1 = __int_as_float(p0.w);
  float w2 = __int_as_float(p1.y), w3 = __int_as_float(p1.w);
  float w4 = __int_as_float(p2.y), w5 = __int_as_float(p2.w);
  float w6 = __int_as_float(p3.y), w7 = __int_as_float(p3.w);
  ax = fmaf(__uint_as_float(v0 << 16), w0, ax); ay = fmaf(__uint_as_float(v0 & 0xffff0000u), w0, ay);
  ax = fmaf(__uint_as_float(v1 << 16), w1, ax); ay = fmaf(__uint_as_float(v1 & 0xffff0000u), w1, ay);
  ax = fmaf(__uint_as_float(v2 << 16), w2, ax); ay = fmaf(__uint_as_float(v2 & 0xffff0000u), w2, ay);
  ax = fmaf(__uint_as_float(v3 << 16), w3, ax); ay = fmaf(__uint_as_float(v3 & 0xffff0000u), w3, ay);
  ax = fmaf(__uint_as_float(v4 << 16), w4, ax); ay = fmaf(__uint_as_float(v4 & 0xffff0000u), w4, ay);
  ax = fmaf(__uint_as_float(v5 << 16), w5, ax); ay = fmaf(__uint_as_float(v5 & 0xffff0000u), w5, ay);
  ax = fmaf(__uint_as_float(v6 << 16), w6, ax); ay = fmaf(__uint_as_float(v6 & 0xffff0000u), w6, ay);
  ax = fmaf(__uint_as_float(v7 << 16), w7, ax); ay = fmaf(__uint_as_float(v7 & 0xffff0000u), w7, ay);
}

// ---------- CSR pull aggregation: TWO nodes per wave, fixed-stride rows ----------
__global__ __launch_bounds__(256) void k_agg(const unsigned* __restrict__ T, const int* __restrict__ degi,
                                             const int2* __restrict__ edg, const float* __restrict__ dinv,
                                             const float* __restrict__ bias, unsigned* __restrict__ H) {
  int pair = blockIdx.x * 4 + (threadIdx.x >> 6);
  int nA = pair * 2, nB = nA + 1;  // NN even, grid covers exactly
  int lane = threadIdx.x & 63;
  float2 b = ((const float2*)bias)[lane];
  float diA = dinv[nA], diB = dinv[nB];
  unsigned tA = T[(size_t)nA * 64 + lane];
  unsigned tB = T[(size_t)nB * 64 + lane];
  float axA = __uint_as_float(tA << 16) * (diA * diA);
  float ayA = __uint_as_float(tA & 0xffff0000u) * (diA * diA);
  float axB = __uint_as_float(tB << 16) * (diB * diB);
  float ayB = __uint_as_float(tB & 0xffff0000u) * (diB * diB);
  int iA = nA * STRIDE, eA = iA + ((degi[nA] + 7) & ~7);
  int iB = nB * STRIDE, eB = iB + ((degi[nB] + 7) & ~7);
  while (iA < eA && iB < eB) {  // paired: 16 gathers + 8 edge-vec loads in flight
    edge8(edg, iA, T, lane, axA, ayA);
    edge8(edg, iB, T, lane, axB, ayB);
    iA += 8; iB += 8;
  }
  for (; iA < eA; iA += 8) edge8(edg, iA, T, lane, axA, ayA);
  for (; iB < eB; iB += 8) edge8(edg, iB, T, lane, axB, ayB);
  H[(size_t)nA * 64 + lane] = pack2bf16(fmaxf(axA + b.x, 0.f), fmaxf(ayA + b.y, 0.f));
  H[(size_t)nB * 64 + lane] = pack2bf16(fmaxf(axB + b.x, 0.f), fmaxf(ayB + b.y, 0.f));
}

extern "C" void kernel_launch(void* const* d_in, const int* in_sizes, int n_in,
                              void* d_out, int out_size, void* d_ws, size_t ws_size,
                              hipStream_t stream) {
  (void)in_sizes; (void)n_in; (void)out_size; (void)ws_size;
  const float* x   = (const float*)d_in[0];
  const int*   ei  = (const int*)d_in[1];
  const float* w1  = (const float*)d_in[2];
  const float* b1  = (const float*)d_in[3];
  const float* w2  = (const float*)d_in[4];
  const float* b2  = (const float*)d_in[5];
  const float* fw1 = (const float*)d_in[6];
  const float* fb1 = (const float*)d_in[7];
  const float* fw2 = (const float*)d_in[8];
  const float* fb2 = (const float*)d_in[9];
  const float* tw  = (const float*)d_in[10];
  const float* tb  = (const float*)d_in[11];
  const int* srcv = ei;
  const int* dstv = ei + NE;

  char* wsb = (char*)d_ws;
  __bf16* bufT = (__bf16*)(wsb + 0);         // 12,800,000 B  [N,128] bf16
  __bf16* hbf  = (__bf16*)(wsb + 12800000);  // 12,800,000 B  [N,128] bf16
  int*    degi = (int*)(wsb + 25600000);     //    200,000 B
  int*    cur  = (int*)(wsb + 25800192);     //    200,000 B
  float*  dinv = (float*)(wsb + 26000640);   //    200,000 B
  int2*   edg  = (int2*)(wsb + 26201088);    // 25,600,000 B (fixed stride 64/node)
  // total ~52 MB of 256 MB ws

  float* y_out = (float*)d_out;              // [5,50000,10]
  float* feat  = (float*)d_out + 2500000;    // [50000,128] feature_x fp32

  // --- CSR build (no scans; mm1 fused with count) ---
  k_zero<<<196, 256, 0, stream>>>(degi);
  k_mm1_count<<<MM1_BLOCKS + (NE + 255) / 256, 256, 0, stream>>>(x, w1, bufT, dstv, degi);
  k_prep<<<196, 256, 0, stream>>>(degi, cur, dinv, edg);
  k_fill<<<(NE + 255) / 256, 256, 0, stream>>>(srcv, dstv, cur, edg, dinv);

  // --- GCN layer 1 aggregation ---
  k_agg<<<6250, 256, 0, stream>>>((const unsigned*)bufT, degi, edg, dinv, b1, (unsigned*)hbf);
  // --- GCN layer 2 ---
  k_mm64<0, true, false><<<1564, 256, 0, stream>>>(hbf, w2, nullptr, bufT, nullptr, NN);
  k_agg<<<6250, 256, 0, stream>>>((const unsigned*)bufT, degi, edg, dinv, b2, (unsigned*)hbf);
  // --- fc1: hbf -> bufT (bf16) + feat (fp32). No in-place (col-split blocks share rows). ---
  k_mm64<3, true, true><<<1564, 256, 0, stream>>>(hbf, fw1, fb1, bufT, feat, NN);
  // --- fc2: bufT -> hbf ---
  k_mm64<3, true, false><<<1564, 256, 0, stream>>>(bufT, fw2, fb2, hbf, nullptr, NN);
  // --- heads: hbf -> y ---
  k_head<<<782, 256, 0, stream>>>(hbf, tw, tb, y_out);
}